// Round 13
// baseline (138.420 us; speedup 1.0000x reference)
//
#include <hip/hip_runtime.h>

#define S    512
#define OUT  512
#define NB   8
#define CB   32
#define WPB  2                       // waves per block
#define NSPP 64                      // stripes per plane (cost-balanced)
#define NBLK (NB * CB * (NSPP / WPB))   // 256 planes * 32 blocks = 8192

// ---------------------------------------------------------------------------
// Kernel 1 (v4, unchanged): wave-per-row inverse-CDF coords + cost-balanced
// stripe boundaries.
// ---------------------------------------------------------------------------
__global__ __launch_bounds__(64) void coords_kernel(
    const float* __restrict__ attx, const float* __restrict__ atty,
    int2* __restrict__ coords,               // [2][8][512]
    int* __restrict__ bnd)                   // [8][65]
{
  __shared__ double sc[S];
  __shared__ int pr[S];
  const int lane = threadIdx.x;              // 0..63
  const int n    = blockIdx.x & 7;
  const int axis = blockIdx.x >> 3;
  const float* att = (axis == 0 ? attx : atty) + n * S;

  double a[8];
#pragma unroll
  for (int k = 0; k < 8; ++k) a[k] = (double)att[lane * 8 + k];

  double tot = 0.0;
#pragma unroll
  for (int k = 0; k < 8; ++k) tot += a[k];
#pragma unroll
  for (int off = 32; off > 0; off >>= 1) tot += __shfl_xor(tot, off);

#pragma unroll
  for (int k = 0; k < 8; ++k) a[k] = a[k] / tot * (double)OUT;
  const double thr = (double)(4 * OUT) / (double)S;   // = 4.0

  for (int it = 0; it < 5; ++it) {
    double s = 0.0;
#pragma unroll
    for (int k = 0; k < 8; ++k) { a[k] = a[k] < thr ? a[k] : thr; s += a[k]; }
#pragma unroll
    for (int off = 32; off > 0; off >>= 1) s += __shfl_xor(s, off);
    const double corr = ((double)OUT - s) / (double)S;
#pragma unroll
    for (int k = 0; k < 8; ++k) a[k] += corr;
  }

  double p[8]; double run = 0.0;
#pragma unroll
  for (int k = 0; k < 8; ++k) { run += a[k]; p[k] = run; }
  double v = run;
#pragma unroll
  for (int off = 1; off < 64; off <<= 1) {
    double t = __shfl_up(v, off);
    if (lane >= off) v += t;
  }
  const double excl = v - run;
#pragma unroll
  for (int k = 0; k < 8; ++k) sc[lane * 8 + k] = excl + p[k];
  __syncthreads();

  const double step = sc[S - 1] / (double)OUT;

  int i0s[8];
#pragma unroll
  for (int k = 0; k < 8; ++k) {
    const int ox = lane * 8 + k;
    const double tgt = step * (double)(ox + 1);

    int lo = 0, hi = S;
    while (lo < hi) {
      int mid = (lo + hi) >> 1;
      if (sc[mid] < tgt) lo = mid + 1; else hi = mid;
    }
    int j = lo < S - 1 ? lo : S - 1;

    double right = sc[j];
    double left  = (j > 0) ? sc[j - 1] : 0.0;
    double denom = right - left;
    if (denom < 1e-8) denom = 1e-8;
    double frac = (tgt - left) / denom;
    frac = frac < 0.0 ? 0.0 : (frac > 1.0 ? 1.0 : frac);

    double pp  = ((double)j + frac) / (double)S * (double)(S - 1);
    double p0f = floor(pp);
    double w   = pp - p0f;
    int i0 = (int)p0f;
    i0 = i0 < 0 ? 0 : (i0 > S - 1 ? S - 1 : i0);
    i0s[k] = i0;

    coords[(axis * NB + n) * S + ox] = make_int2(i0, __float_as_int((float)w));
  }

  // ---- axis==1: cost-balanced stripe boundaries for the sampler ----
  if (axis == 1) {
    const int fromPrev = __shfl_up(i0s[7], 1);
    int prevv = (lane == 0) ? (i0s[0] - 2) : fromPrev;  // oy=0 is a jump
    int cinc[8]; int runc = 0;
#pragma unroll
    for (int k = 0; k < 8; ++k) {
      const int d = i0s[k] - prevv;
      const int c = 1 + (d <= 0 ? 0 : (d == 1 ? 1 : 2));
      runc += c; cinc[k] = runc; prevv = i0s[k];
    }
    int vv = runc;
#pragma unroll
    for (int off = 1; off < 64; off <<= 1) {
      const int t = __shfl_up(vv, off);
      if (lane >= off) vv += t;
    }
    const int exclc = vv - runc;
#pragma unroll
    for (int k = 0; k < 8; ++k) pr[lane * 8 + k] = exclc + cinc[k];
    __syncthreads();

    const int Ctot = pr[S - 1];
    const int tgt = (int)(((long long)lane * Ctot) / NSPP);
    int lo = 0, hi = S;
    while (lo < hi) {
      const int mid = (lo + hi) >> 1;
      if (pr[mid] <= tgt) lo = mid + 1; else hi = mid;
    }
    bnd[n * (NSPP + 1) + lane] = lo;
    if (lane == 63) bnd[n * (NSPP + 1) + NSPP] = S;
  }
}

// ---------------------------------------------------------------------------
// Kernel 2 (v13 = v12 + one-iteration software pipeline): the loads for
// output row oy+1 are issued right after row oy's registers are committed
// to LDS, so each global load gets a full gather+lerp+store phase (plus
// TLP) of latency cover before its ds_write consumes it. Indices come from
// coords (not loaded data), so the pipeline needs no extra register slots:
// the same 16 staging VGPRs simply live one iteration longer. Everything
// else (balanced stripes, sliding window, nt stores, XCD swizzle) is v12.
// ---------------------------------------------------------------------------
__global__ __launch_bounds__(128) void sample_kernel(
    const float* __restrict__ data, const int2* __restrict__ coords,
    const int* __restrict__ bnd, float* __restrict__ out)
{
  __shared__ float bufA_[WPB][S + 1];
  __shared__ float bufB_[WPB][S + 1];

  int b = (int)blockIdx.x;
  b = (b & 7) * (NBLK / 8) + (b >> 3);       // bijective XCD swizzle
  const int plane = b >> 5;                  // n*CB + c   (32 blocks/plane)
  const int bip   = b & 31;                  // block-in-plane
  const int n     = plane >> 5;

  const int tid  = threadIdx.x;
  const int wv   = tid >> 6;                 // 0..1
  const int lane = tid & 63;
  const int s    = bip * WPB + wv;           // stripe 0..63
  const int oy0   = bnd[n * (NSPP + 1) + s];
  const int oyend = bnd[n * (NSPP + 1) + s + 1];
  if (oy0 >= oyend) return;

  const float* __restrict__ pl = data + (size_t)plane * (S * S);
  float* __restrict__       po = out  + (size_t)plane * (S * S);

  // hoisted x coords: lane handles ox = lane + 64k
  int   ix[8];
  float wx[8];
#pragma unroll
  for (int k = 0; k < 8; ++k) {
    const int2 cx = coords[n * S + lane + 64 * k];
    ix[k] = cx.x;
    wx[k] = __int_as_float(cx.y);
  }

  float* bufA = bufA_[wv];
  float* bufB = bufB_[wv];
  const int2* __restrict__ cyp = coords + (NB + n) * S;

  float CxA[8], CxB[8];
  float4 qA0, qA1, qB0, qB1;                 // single in-flight staging slot

  // ---- prologue: issue loads for row oy0 (always a jump) ----
  int prevA;
  int tcur;                                  // type of the row the regs hold
  float wyc;                                 // its y-weight
  {
    const int2 c = cyp[oy0];
    const int a = c.x;
    wyc = __int_as_float(c.y);
    const int rb = (a + 1 < S) ? a + 1 : S - 1;
    const float4* RA = (const float4*)(pl + (size_t)a  * S);
    const float4* RB = (const float4*)(pl + (size_t)rb * S);
    qA0 = RA[lane]; qA1 = RA[lane + 64];
    qB0 = RB[lane]; qB1 = RB[lane + 64];
    tcur = 2;
    prevA = a;
  }

  for (int oy = oy0; oy < oyend; ++oy) {
    // 1) commit the pending registers (row oy) to wave-private LDS
    if (tcur == 2) {
      ((float4*)bufA)[lane]      = qA0;
      ((float4*)bufA)[lane + 64] = qA1;
      ((float4*)bufB)[lane]      = qB0;
      ((float4*)bufB)[lane + 64] = qB1;
      if (lane == 63) { bufA[S] = qA1.w; bufB[S] = qB1.w; }
    } else if (tcur == 1) {
      ((float4*)bufB)[lane]      = qB0;
      ((float4*)bufB)[lane + 64] = qB1;
      if (lane == 63) bufB[S] = qB1.w;
    }

    // 2) issue loads for row oy+1 (regs are free after the ds_write above);
    //    they have the whole gather+lerp+store phase below to land.
    int tnext = 0;
    float wyn = 0.0f;
    if (oy + 1 < oyend) {
      const int2 c = cyp[oy + 1];
      const int a = c.x;
      wyn = __int_as_float(c.y);
      if (a != prevA) {
        const int rb = (a + 1 < S) ? a + 1 : S - 1;
        const float4* RB = (const float4*)(pl + (size_t)rb * S);
        qB0 = RB[lane]; qB1 = RB[lane + 64];
        if (a == prevA + 1) {
          tnext = 1;
        } else {
          const float4* RA = (const float4*)(pl + (size_t)a * S);
          qA0 = RA[lane]; qA1 = RA[lane + 64];
          tnext = 2;
        }
        prevA = a;
      }
    }

    // 3) gather row oy from LDS (x-lerp into registers)
    if (tcur == 2) {
#pragma unroll
      for (int k = 0; k < 8; ++k) {
        const float x0 = bufA[ix[k]];
        const float x1 = bufA[ix[k] + 1];
        CxA[k] = x0 + wx[k] * (x1 - x0);
      }
#pragma unroll
      for (int k = 0; k < 8; ++k) {
        const float x0 = bufB[ix[k]];
        const float x1 = bufB[ix[k] + 1];
        CxB[k] = x0 + wx[k] * (x1 - x0);
      }
    } else if (tcur == 1) {
#pragma unroll
      for (int k = 0; k < 8; ++k) CxA[k] = CxB[k];
#pragma unroll
      for (int k = 0; k < 8; ++k) {
        const float x0 = bufB[ix[k]];
        const float x1 = bufB[ix[k] + 1];
        CxB[k] = x0 + wx[k] * (x1 - x0);
      }
    }

    // 4) y-lerp + coalesced NONTEMPORAL stores
    float* orow = po + (size_t)oy * OUT;
#pragma unroll
    for (int k = 0; k < 8; ++k)
      __builtin_nontemporal_store(CxA[k] + wyc * (CxB[k] - CxA[k]),
                                  orow + lane + 64 * k);

    tcur = tnext;
    wyc  = wyn;
  }
}

extern "C" void kernel_launch(void* const* d_in, const int* in_sizes, int n_in,
                              void* d_out, int out_size, void* d_ws, size_t ws_size,
                              hipStream_t stream) {
  const float* data = (const float*)d_in[0];
  const float* attx = (const float*)d_in[1];
  const float* atty = (const float*)d_in[2];
  float* out = (float*)d_out;

  // Workspace: int2 coords[2][8][512] (64 KB) then int bnd[8][65] (~2 KB)
  int2* coords = (int2*)d_ws;
  int*  bnd    = (int*)((char*)d_ws + 2 * NB * S * sizeof(int2));

  coords_kernel<<<16, 64, 0, stream>>>(attx, atty, coords, bnd);

  sample_kernel<<<NBLK, 128, 0, stream>>>(data, coords, bnd, out);
}

// Round 14
// 98.656 us; speedup vs baseline: 1.4030x; 1.4030x over previous
//
#include <hip/hip_runtime.h>

#define S    512
#define OUT  512
#define NB   8
#define CB   32
#define TRW  8                       // rows per wave
#define WPB  2                       // waves per block (fine dispatch grain)
#define NBLK (NB * CB * 32)          // 256 planes * 32 blocks/plane = 8192

// ---------------------------------------------------------------------------
// Kernel 1 (v3): wave-per-row inverse-CDF coords, register-resident.
// 16 blocks x 64 threads; block = (axis, n). Each lane owns 8 cells.
// All reductions via shuffles; LDS only holds the final cumsum for the
// per-output binary search. Output packed: int2 {i0, bits(w)}.
// ---------------------------------------------------------------------------
__global__ __launch_bounds__(64) void coords_kernel(
    const float* __restrict__ attx, const float* __restrict__ atty,
    int2* __restrict__ coords)               // [2][8][512]
{
  __shared__ double sc[S];
  const int lane = threadIdx.x;              // 0..63
  const int n    = blockIdx.x & 7;
  const int axis = blockIdx.x >> 3;
  const float* att = (axis == 0 ? attx : atty) + n * S;

  double a[8];
#pragma unroll
  for (int k = 0; k < 8; ++k) a[k] = (double)att[lane * 8 + k];

  double tot = 0.0;
#pragma unroll
  for (int k = 0; k < 8; ++k) tot += a[k];
#pragma unroll
  for (int off = 32; off > 0; off >>= 1) tot += __shfl_xor(tot, off);

#pragma unroll
  for (int k = 0; k < 8; ++k) a[k] = a[k] / tot * (double)OUT;
  const double thr = (double)(4 * OUT) / (double)S;   // = 4.0

  for (int it = 0; it < 5; ++it) {
    double s = 0.0;
#pragma unroll
    for (int k = 0; k < 8; ++k) { a[k] = a[k] < thr ? a[k] : thr; s += a[k]; }
#pragma unroll
    for (int off = 32; off > 0; off >>= 1) s += __shfl_xor(s, off);
    const double corr = ((double)OUT - s) / (double)S;
#pragma unroll
    for (int k = 0; k < 8; ++k) a[k] += corr;
  }

  double p[8]; double run = 0.0;
#pragma unroll
  for (int k = 0; k < 8; ++k) { run += a[k]; p[k] = run; }
  double v = run;
#pragma unroll
  for (int off = 1; off < 64; off <<= 1) {
    double t = __shfl_up(v, off);
    if (lane >= off) v += t;
  }
  const double excl = v - run;
#pragma unroll
  for (int k = 0; k < 8; ++k) sc[lane * 8 + k] = excl + p[k];
  __syncthreads();

  const double step = sc[S - 1] / (double)OUT;

#pragma unroll
  for (int k = 0; k < 8; ++k) {
    const int ox = lane * 8 + k;
    const double tgt = step * (double)(ox + 1);

    int lo = 0, hi = S;
    while (lo < hi) {
      int mid = (lo + hi) >> 1;
      if (sc[mid] < tgt) lo = mid + 1; else hi = mid;
    }
    int j = lo < S - 1 ? lo : S - 1;

    double right = sc[j];
    double left  = (j > 0) ? sc[j - 1] : 0.0;
    double denom = right - left;
    if (denom < 1e-8) denom = 1e-8;
    double frac = (tgt - left) / denom;
    frac = frac < 0.0 ? 0.0 : (frac > 1.0 ? 1.0 : frac);

    double pp  = ((double)j + frac) / (double)S * (double)(S - 1);
    double p0f = floor(pp);
    double w   = pp - p0f;
    int i0 = (int)p0f;
    i0 = i0 < 0 ? 0 : (i0 > S - 1 ? S - 1 : i0);

    coords[(axis * NB + n) * S + ox] = make_int2(i0, __float_as_int((float)w));
  }
}

// ---------------------------------------------------------------------------
// Kernel 2 (v14 = v11, the measured best): sliding-window Cx reuse,
// barrier-free, wave-private, nontemporal stores. 2 waves/block * 8192
// blocks (TRW=8): fine dispatch grain, full 32-wave/CU TLP. Pipeline
// depth deliberately 0 — depths 1/2 measured equal-or-worse (v6,v9,v13);
// TLP covers the staging latency, and extra liveness costs occupancy.
// ---------------------------------------------------------------------------
__global__ __launch_bounds__(128) void sample_kernel(
    const float* __restrict__ data, const int2* __restrict__ coords,
    float* __restrict__ out)
{
  __shared__ float bufA_[WPB][S + 1];
  __shared__ float bufB_[WPB][S + 1];

  int b = (int)blockIdx.x;
  b = (b & 7) * (NBLK / 8) + (b >> 3);       // bijective XCD swizzle
  const int plane = b >> 5;                  // n*CB + c   (32 blocks/plane)
  const int bip   = b & 31;                  // block-in-plane
  const int n     = plane >> 5;

  const int tid  = threadIdx.x;
  const int wv   = tid >> 6;                 // 0..1
  const int lane = tid & 63;
  const int oy0  = (bip * WPB + wv) * TRW;

  const float* __restrict__ pl = data + (size_t)plane * (S * S);
  float* __restrict__       po = out  + (size_t)plane * (S * S);

  // hoisted x coords: lane handles ox = lane + 64k
  int   ix[8];
  float wx[8];
#pragma unroll
  for (int k = 0; k < 8; ++k) {
    const int2 cx = coords[n * S + lane + 64 * k];
    ix[k] = cx.x;
    wx[k] = __int_as_float(cx.y);
  }

  float* bufA = bufA_[wv];
  float* bufB = bufB_[wv];
  const int2* __restrict__ cyp = coords + (NB + n) * S + oy0;

  float CxA[8], CxB[8];
  int curA = -1000;                          // forces jump path at r=0

  for (int r = 0; r < TRW; ++r) {
    const int2 cy = cyp[r];                  // wave-uniform
    const int   a  = cy.x;
    const float wy = __int_as_float(cy.y);

    if (a != curA) {
      const int rowB = (a + 1 < S) ? a + 1 : S - 1;
      if (a == curA + 1) {
        // +1 advance: old B row becomes new A row — shift registers
#pragma unroll
        for (int k = 0; k < 8; ++k) CxA[k] = CxB[k];
        const float4* RB = (const float4*)(pl + (size_t)rowB * S);
        const float4 p0 = RB[lane];
        const float4 p1 = RB[lane + 64];
        ((float4*)bufB)[lane]      = p0;
        ((float4*)bufB)[lane + 64] = p1;
        if (lane == 63) bufB[S] = p1.w;      // pad: clamp to last element
#pragma unroll
        for (int k = 0; k < 8; ++k) {
          const float x0 = bufB[ix[k]];
          const float x1 = bufB[ix[k] + 1];
          CxB[k] = x0 + wx[k] * (x1 - x0);
        }
      } else {
        // jump: load + stage + gather both rows (loads issue back-to-back)
        const float4* RA = (const float4*)(pl + (size_t)a    * S);
        const float4* RB = (const float4*)(pl + (size_t)rowB * S);
        const float4 q0 = RA[lane];
        const float4 q1 = RA[lane + 64];
        const float4 p0 = RB[lane];
        const float4 p1 = RB[lane + 64];
        ((float4*)bufA)[lane]      = q0;
        ((float4*)bufA)[lane + 64] = q1;
        ((float4*)bufB)[lane]      = p0;
        ((float4*)bufB)[lane + 64] = p1;
        if (lane == 63) { bufA[S] = q1.w; bufB[S] = p1.w; }
#pragma unroll
        for (int k = 0; k < 8; ++k) {
          const float x0 = bufA[ix[k]];
          const float x1 = bufA[ix[k] + 1];
          CxA[k] = x0 + wx[k] * (x1 - x0);
        }
#pragma unroll
        for (int k = 0; k < 8; ++k) {
          const float x0 = bufB[ix[k]];
          const float x1 = bufB[ix[k] + 1];
          CxB[k] = x0 + wx[k] * (x1 - x0);
        }
      }
      curA = a;
    }

    // y-lerp + coalesced NONTEMPORAL stores (wave covers the full 2 KB row)
    float* orow = po + (size_t)(oy0 + r) * OUT;
#pragma unroll
    for (int k = 0; k < 8; ++k)
      __builtin_nontemporal_store(CxA[k] + wy * (CxB[k] - CxA[k]),
                                  orow + lane + 64 * k);
  }
}

extern "C" void kernel_launch(void* const* d_in, const int* in_sizes, int n_in,
                              void* d_out, int out_size, void* d_ws, size_t ws_size,
                              hipStream_t stream) {
  const float* data = (const float*)d_in[0];
  const float* attx = (const float*)d_in[1];
  const float* atty = (const float*)d_in[2];
  float* out = (float*)d_out;

  // Workspace: int2 coords[2][8][512]  (x coords then y coords), 64 KB
  int2* coords = (int2*)d_ws;

  coords_kernel<<<16, 64, 0, stream>>>(attx, atty, coords);

  sample_kernel<<<NBLK, 128, 0, stream>>>(data, coords, out);
}